// Round 9
// baseline (310.611 us; speedup 1.0000x reference)
//
#include <hip/hip_runtime.h>
#include <stdint.h>
#include <stddef.h>

#define N_TOK 16384
#define DM    1024
#define DFF   4096
#define NT    4
#define TU    1024   // d_ff tile
#define TD    256    // d_model tile

typedef __attribute__((ext_vector_type(8))) short  short8;
typedef __attribute__((ext_vector_type(4))) short  short4v;
typedef __attribute__((ext_vector_type(4))) float  floatx4;

__device__ inline unsigned short f2bf(float f){
  union { float f; uint32_t u; } v; v.f = f;
  uint32_t u = v.u + 0x7FFFu + ((v.u >> 16) & 1u);   // RNE
  return (unsigned short)(u >> 16);
}

// async global->LDS, 16B per lane; lds dest is wave-uniform, lane i lands at +16*i
__device__ __forceinline__ void gll16(const void* g, void* l){
  __builtin_amdgcn_global_load_lds(
      (const __attribute__((address_space(1))) unsigned int*)g,
      (__attribute__((address_space(3))) unsigned int*)l,
      16, 0, 0);
}

// ---------------- signatures: partial column sums of w_up + bf16 convert ----
__global__ void k_sig_partial(const float* __restrict__ w_up,
                              float* __restrict__ partial,
                              unsigned short* __restrict__ wupb){
  const int b = blockIdx.x, tid = threadIdx.x;
  const int tile = b >> 6, chunk = b & 63;
  const int c0 = tid * 4;
  const int row0 = tile*TU + chunk*16;
  float s0=0.f, s1=0.f, s2=0.f, s3=0.f;
  const float* base = w_up + (size_t)row0 * DM + c0;
  #pragma unroll
  for (int r = 0; r < 16; ++r){
    floatx4 v = *(const floatx4*)(base + (size_t)r * DM);
    s0 += v[0]; s1 += v[1]; s2 += v[2]; s3 += v[3];
    short4v p;
    p[0]=(short)f2bf(v[0]); p[1]=(short)f2bf(v[1]);
    p[2]=(short)f2bf(v[2]); p[3]=(short)f2bf(v[3]);
    *(short4v*)(wupb + (size_t)(row0 + r) * DM + c0) = p;
  }
  float* p = partial + ((size_t)tile*DM + c0) * 64 + chunk;
  p[0] = s0; p[64] = s1; p[128] = s2; p[192] = s3;
}

__global__ void k_sig_final(const float* __restrict__ partial,
                            float* __restrict__ sig){
  const int g = blockIdx.x * 256 + threadIdx.x;   // 0..4095 = tile*1024+col
  const float* p = partial + (size_t)g * 64;
  float s = 0.f;
  #pragma unroll
  for (int i = 0; i < 64; ++i) s += p[i];
  sig[g] = (s > 0.f) ? 1.f : ((s < 0.f) ? -1.f : 0.f);
}

// ---------------- w_down -> bf16 ------------------------------------------
__global__ void k_wdown_conv(const float* __restrict__ w,
                             unsigned short* __restrict__ wb){
  const size_t i = ((size_t)blockIdx.x * 256 + threadIdx.x) * 8;
  floatx4 v0 = *(const floatx4*)(w + i);
  floatx4 v1 = *(const floatx4*)(w + i + 4);
  short8 p;
  p[0]=(short)f2bf(v0[0]); p[1]=(short)f2bf(v0[1]); p[2]=(short)f2bf(v0[2]); p[3]=(short)f2bf(v0[3]);
  p[4]=(short)f2bf(v1[0]); p[5]=(short)f2bf(v1[1]); p[6]=(short)f2bf(v1[2]); p[7]=(short)f2bf(v1[3]);
  *(short8*)(wb + i) = p;
}

// ---------------- routing: fp64 scores + x->bf16 emit -----------------------
// xbf row n lives in SECOND 2048B of out row n (ushort offset n*2048 + 1024).
__global__ __launch_bounds__(256) void k_route(
    const float* __restrict__ x, const float* __restrict__ sig,
    float* __restrict__ gate_out, int* __restrict__ winner,
    unsigned short* __restrict__ xbf){
  __shared__ float ssig[NT * DM];
  const int tid = threadIdx.x;
  for (int i = tid; i < NT*DM; i += 256) ssig[i] = sig[i];
  __syncthreads();
  const int wv = tid >> 6, lane = tid & 63;
  const int n = blockIdx.x * 4 + wv;
  const float* xr = x + (size_t)n * DM;
  unsigned short* xb = xbf + (size_t)n * 2048 + 1024;
  double a0=0.0, a1=0.0, a2=0.0, a3=0.0;
  #pragma unroll
  for (int j = 0; j < 4; ++j){
    const int c = j*256 + lane*4;
    floatx4 v = *(const floatx4*)(xr + c);
    short4v p;
    p[0]=(short)f2bf(v[0]); p[1]=(short)f2bf(v[1]);
    p[2]=(short)f2bf(v[2]); p[3]=(short)f2bf(v[3]);
    *(short4v*)(xb + c) = p;
    #pragma unroll
    for (int u = 0; u < 4; ++u){
      double xv = (double)v[u];
      a0 += xv * (double)ssig[c+u];
      a1 += xv * (double)ssig[DM   + c+u];
      a2 += xv * (double)ssig[2*DM + c+u];
      a3 += xv * (double)ssig[3*DM + c+u];
    }
  }
  #pragma unroll
  for (int off = 32; off > 0; off >>= 1){
    a0 += __shfl_down(a0, off, 64);
    a1 += __shfl_down(a1, off, 64);
    a2 += __shfl_down(a2, off, 64);
    a3 += __shfl_down(a3, off, 64);
  }
  if (lane == 0){
    double s[4] = {a0, a1, a2, a3};
    int w = 0;
    #pragma unroll
    for (int t = 1; t < 4; ++t) if (s[t] > s[w]) w = t;   // first-max tiebreak
    floatx4 g = { w==0 ? 1.f:0.f, w==1 ? 1.f:0.f, w==2 ? 1.f:0.f, w==3 ? 1.f:0.f };
    *(floatx4*)(gate_out + (size_t)n * 4) = g;
    winner[n] = w;
  }
}

// ---------------- histogram / scan / scatter (atomic-free) ------------------
__global__ void k_hist(const int* __restrict__ winner,
                       int* __restrict__ blk_cnt){   // [64][4]
  __shared__ int wcnt[4][NT];
  const int tid = threadIdx.x, wv = tid >> 6, lane = tid & 63;
  const int w = winner[blockIdx.x * 256 + tid];
  #pragma unroll
  for (int t = 0; t < NT; ++t){
    unsigned long long m = __ballot(w == t);
    if (lane == 0) wcnt[wv][t] = __popcll(m);
  }
  __syncthreads();
  if (tid < NT){
    int s = wcnt[0][tid] + wcnt[1][tid] + wcnt[2][tid] + wcnt[3][tid];
    blk_cnt[blockIdx.x * NT + tid] = s;
  }
}

__global__ void k_scan(const int* __restrict__ blk_cnt,
                       int* __restrict__ meta, int* __restrict__ blk_base){
  if (threadIdx.x == 0){
    int tot[NT] = {0,0,0,0};
    for (int b = 0; b < 64; ++b)
      for (int t = 0; t < NT; ++t) tot[t] += blk_cnt[b*NT + t];
    int off = 0;
    for (int t = 0; t < NT; ++t){ meta[t] = tot[t]; meta[4+t] = off; off += tot[t]; }
    int run[NT];
    for (int t = 0; t < NT; ++t) run[t] = meta[4+t];
    for (int b = 0; b < 64; ++b)
      for (int t = 0; t < NT; ++t){ blk_base[b*NT + t] = run[t]; run[t] += blk_cnt[b*NT + t]; }
  }
}

__global__ void k_scatter(const int* __restrict__ winner,
                          const int* __restrict__ blk_base,
                          int* __restrict__ idx){
  __shared__ int wcnt[4][NT];
  const int tid = threadIdx.x, wv = tid >> 6, lane = tid & 63;
  const int n = blockIdx.x * 256 + tid;
  const int w = winner[n];
  unsigned long long mymask = 0;
  #pragma unroll
  for (int t = 0; t < NT; ++t){
    unsigned long long m = __ballot(w == t);
    if (lane == 0) wcnt[wv][t] = __popcll(m);
    if (t == w) mymask = m;
  }
  __syncthreads();
  const unsigned long long below = (lane == 0) ? 0ull : (~0ull >> (64 - lane));
  int pos = blk_base[blockIdx.x * NT + w] + __popcll(mymask & below);
  for (int v = 0; v < wv; ++v) pos += wcnt[v][w];
  idx[pos] = n;
}

// ---------------- GEMM1: hid = relu(xbf[rows] @ wupb[tile]^T + b_up) --------
// BM=128 BN=128; gll16 staging, BK=64 paired buffers; 4 blocks/CU resident
// (LDS 4x33KB=133KB<160; VGPR 64 arch + 64 acc = 128/wave fits 4 waves/SIMD).
__global__ __launch_bounds__(256, 4) void k_gemm1(
    const unsigned short* __restrict__ xbf,   // (ushort*)d_out; row n at n*2048+1024
    const unsigned short* __restrict__ wupb,  // [4096][1024] bf16
    const float* __restrict__ b_up, const int* __restrict__ meta,
    const int* __restrict__ idx, unsigned short* __restrict__ hid){
  const int tile = blockIdx.z;
  const int cnt  = meta[tile];
  const int p0   = blockIdx.x * 128;
  if (p0 >= cnt) return;
  const int off  = meta[4 + tile];
  const int nb   = blockIdx.y;

  __shared__ unsigned short smem[16384];  // As0|As1|Bs0|Bs1 (4096 ushorts each); epi overlays
  unsigned short* As0 = smem;
  unsigned short* As1 = smem + 4096;
  unsigned short* Bs0 = smem + 8192;
  unsigned short* Bs1 = smem + 12288;
  __shared__ int nrow[128];

  const int tid = threadIdx.x;
  if (tid < 128){
    int p = p0 + tid;
    nrow[tid] = idx[off + (p < cnt ? p : cnt - 1)];
  }
  __syncthreads();

  const int wv = tid >> 6, lane = tid & 63;
  const int wm = (wv >> 1) * 64, wn = (wv & 1) * 64;
  const int l16 = lane & 15, quad = lane >> 4;

  const int rsub = lane >> 2;          // 0..15
  const int kus  = (lane & 3) * 8;     // ushort offset within 32-elem row

  const int ra = wv*32 + rsub;
  const unsigned short* aptr0 = xbf + (size_t)nrow[ra]      * 2048 + 1024 + kus;
  const unsigned short* aptr1 = xbf + (size_t)nrow[ra + 16] * 2048 + 1024 + kus;
  const unsigned short* bptr0 = wupb + (size_t)(tile*TU + nb*128 + wv*32 + rsub) * DM + kus;
  const unsigned short* bptr1 = bptr0 + 16 * DM;

  // wave-uniform LDS dests ([row][32] layout, 64B row stride)
  unsigned short* a0d0 = As0 + (wv*32) * 32;  unsigned short* a0d1 = a0d0 + 16*32;
  unsigned short* a1d0 = As1 + (wv*32) * 32;  unsigned short* a1d1 = a1d0 + 16*32;
  unsigned short* b0d0 = Bs0 + (wv*32) * 32;  unsigned short* b0d1 = b0d0 + 16*32;
  unsigned short* b1d0 = Bs1 + (wv*32) * 32;  unsigned short* b1d1 = b1d0 + 16*32;

  floatx4 acc[4][4];
  #pragma unroll
  for (int i = 0; i < 4; ++i)
    #pragma unroll
    for (int j = 0; j < 4; ++j) acc[i][j] = (floatx4){0.f,0.f,0.f,0.f};

  for (int k0 = 0; k0 < DM; k0 += 64){
    gll16(aptr0 + k0,      a0d0);
    gll16(aptr1 + k0,      a0d1);
    gll16(aptr0 + k0 + 32, a1d0);
    gll16(aptr1 + k0 + 32, a1d1);
    gll16(bptr0 + k0,      b0d0);
    gll16(bptr1 + k0,      b0d1);
    gll16(bptr0 + k0 + 32, b1d0);
    gll16(bptr1 + k0 + 32, b1d1);
    __syncthreads();
    {
      short8 af[4], bfr[4];
      #pragma unroll
      for (int i = 0; i < 4; ++i) af[i]  = *(const short8*)(As0 + (wm + i*16 + l16)*32 + quad*8);
      #pragma unroll
      for (int j = 0; j < 4; ++j) bfr[j] = *(const short8*)(Bs0 + (wn + j*16 + l16)*32 + quad*8);
      #pragma unroll
      for (int i = 0; i < 4; ++i)
        #pragma unroll
        for (int j = 0; j < 4; ++j)
          acc[i][j] = __builtin_amdgcn_mfma_f32_16x16x32_bf16(af[i], bfr[j], acc[i][j], 0, 0, 0);
    }
    {
      short8 af[4], bfr[4];
      #pragma unroll
      for (int i = 0; i < 4; ++i) af[i]  = *(const short8*)(As1 + (wm + i*16 + l16)*32 + quad*8);
      #pragma unroll
      for (int j = 0; j < 4; ++j) bfr[j] = *(const short8*)(Bs1 + (wn + j*16 + l16)*32 + quad*8);
      #pragma unroll
      for (int i = 0; i < 4; ++i)
        #pragma unroll
        for (int j = 0; j < 4; ++j)
          acc[i][j] = __builtin_amdgcn_mfma_f32_16x16x32_bf16(af[i], bfr[j], acc[i][j], 0, 0, 0);
    }
    __syncthreads();
  }

  // epilogue: two half-passes of 64 rows through LDS (pad stride 136), wide stores
  const int gcol0 = nb*128;
  #pragma unroll
  for (int half = 0; half < 2; ++half){
    if ((wv >> 1) == half){
      #pragma unroll
      for (int i = 0; i < 4; ++i){
        #pragma unroll
        for (int j = 0; j < 4; ++j){
          const int col = wn + j*16 + l16;          // 0..127
          const float bias = b_up[tile*TU + gcol0 + col];
          #pragma unroll
          for (int r = 0; r < 4; ++r){
            const int lrow = i*16 + quad*4 + r;     // 0..63
            float v = acc[i][j][r] + bias;
            smem[lrow*136 + col] = f2bf(v > 0.f ? v : 0.f);
          }
        }
      }
    }
    __syncthreads();
    // 64 rows x 16 chunks of 8 ushorts (128 cols)
    #pragma unroll
    for (int c = tid; c < 1024; c += 256){
      const int lrow = c >> 4, k8 = (c & 15) * 8;
      const int m = half*64 + lrow;
      if (p0 + m < cnt){
        short8 vv = *(const short8*)(smem + lrow*136 + k8);
        *(short8*)(hid + (size_t)nrow[m]*2048 + gcol0 + k8) = vv;
      }
    }
    __syncthreads();
  }
}

// ---------------- GEMM2: out = hid @ wdownb[tile]^T + b_down + zero-fill ----
// BM=32 BN=256, BK=64 paired buffers (16 iters x 16 MFMA). Zero-fill fused
// after the K-loop's final barrier (all hid global reads drained; each
// token's hid is read by exactly this one block).
__global__ __launch_bounds__(256, 2) void k_gemm2(
    const unsigned short* __restrict__ hid,    // (ushort*)d_out; row n at n*2048
    const unsigned short* __restrict__ wdownb, // [1024][4096] bf16
    const float* __restrict__ b_down, const int* __restrict__ meta,
    const int* __restrict__ idx, float* __restrict__ out){
  const int tile = blockIdx.z;
  const int cnt  = meta[tile];
  const int p0   = blockIdx.x * 32;
  if (p0 >= cnt) return;
  const int off  = meta[4 + tile];

  __shared__ unsigned short smem[18432];  // As0|As1 (1024 each) | Bs0|Bs1 (8192 each)
  unsigned short* As0 = smem;
  unsigned short* As1 = smem + 1024;
  unsigned short* Bs0 = smem + 2048;
  unsigned short* Bs1 = smem + 10240;
  float* epi = (float*)smem;              // overlay: 16 rows x 260 floats = 16640B
  __shared__ int nrow[32];

  const int tid = threadIdx.x;
  if (tid < 32){
    int p = p0 + tid;
    nrow[tid] = idx[off + (p < cnt ? p : cnt - 1)];
  }
  __syncthreads();

  const int wv = tid >> 6, lane = tid & 63;
  const int wn = wv * 64;
  const int l16 = lane & 15, quad = lane >> 4;

  const int rsub = lane >> 2;
  const int kus  = (lane & 3) * 8;

  // A: waves 0,1 stage chunk0 (rows 0-15 / 16-31); waves 2,3 stage chunk1
  const int arow = (wv & 1)*16 + rsub;
  const unsigned short* aptr = hid + (size_t)nrow[arow] * 2048 + kus;
  const int aoff = (wv >> 1) * 32;                     // k-chunk offset
  unsigned short* asd = (wv < 2 ? As0 : As1) + ((wv & 1)*16) * 32;
  // B: 256 rows, 64 per wave per chunk
  const unsigned short* bptr = wdownb + (size_t)(tile*TD + wv*64 + rsub) * DFF + tile*TU + kus;
  unsigned short* bsd0 = Bs0 + (wv*64) * 32;
  unsigned short* bsd1 = Bs1 + (wv*64) * 32;

  floatx4 acc[2][4];
  #pragma unroll
  for (int i = 0; i < 2; ++i)
    #pragma unroll
    for (int j = 0; j < 4; ++j) acc[i][j] = (floatx4){0.f,0.f,0.f,0.f};

  for (int k0 = 0; k0 < TU; k0 += 64){
    gll16(aptr + k0 + aoff, asd);
    gll16(bptr + k0,               bsd0);
    gll16(bptr + k0 + 16*DFF,      bsd0 + 16*32);
    gll16(bptr + k0 + 32*DFF,      bsd0 + 32*32);
    gll16(bptr + k0 + 48*DFF,      bsd0 + 48*32);
    gll16(bptr + k0 + 32,          bsd1);
    gll16(bptr + k0 + 32 + 16*DFF, bsd1 + 16*32);
    gll16(bptr + k0 + 32 + 32*DFF, bsd1 + 32*32);
    gll16(bptr + k0 + 32 + 48*DFF, bsd1 + 48*32);
    __syncthreads();
    {
      short8 af[2], bfr[4];
      #pragma unroll
      for (int i = 0; i < 2; ++i) af[i]  = *(const short8*)(As0 + (i*16 + l16)*32 + quad*8);
      #pragma unroll
      for (int j = 0; j < 4; ++j) bfr[j] = *(const short8*)(Bs0 + (wn + j*16 + l16)*32 + quad*8);
      #pragma unroll
      for (int i = 0; i < 2; ++i)
        #pragma unroll
        for (int j = 0; j < 4; ++j)
          acc[i][j] = __builtin_amdgcn_mfma_f32_16x16x32_bf16(af[i], bfr[j], acc[i][j], 0, 0, 0);
    }
    {
      short8 af[2], bfr[4];
      #pragma unroll
      for (int i = 0; i < 2; ++i) af[i]  = *(const short8*)(As1 + (i*16 + l16)*32 + quad*8);
      #pragma unroll
      for (int j = 0; j < 4; ++j) bfr[j] = *(const short8*)(Bs1 + (wn + j*16 + l16)*32 + quad*8);
      #pragma unroll
      for (int i = 0; i < 2; ++i)
        #pragma unroll
        for (int j = 0; j < 4; ++j)
          acc[i][j] = __builtin_amdgcn_mfma_f32_16x16x32_bf16(af[i], bfr[j], acc[i][j], 0, 0, 0);
    }
    __syncthreads();
  }

  // zero-fill non-winner 256-col blocks of OWN tokens (hid reads all drained)
  const floatx4 z4 = {0.f, 0.f, 0.f, 0.f};
  #pragma unroll
  for (int cb = 0; cb < 4; ++cb){
    if (cb == tile) continue;
    for (int c = tid; c < 32*64; c += 256){
      const int rowl = c >> 6, c4 = (c & 63) * 4;
      if (p0 + rowl < cnt)
        *(floatx4*)(out + (size_t)nrow[rowl]*DM + cb*256 + c4) = z4;
    }
  }

  // epilogue: two half-passes of 16 rows via LDS fp32 (pad stride 260), float4 stores
  #pragma unroll
  for (int half = 0; half < 2; ++half){
    #pragma unroll
    for (int j = 0; j < 4; ++j){
      const int col = wn + j*16 + l16;              // 0..255
      const float bias = b_down[tile*TD + col];
      #pragma unroll
      for (int r = 0; r < 4; ++r){
        const int lrow = quad*4 + r;                // 0..15
        epi[lrow*260 + col] = acc[half][j][r] + bias;
      }
    }
    __syncthreads();
    #pragma unroll
    for (int c = tid; c < 1024; c += 256){          // 16 rows x 64 float4 chunks
      const int lrow = c >> 6, c4 = (c & 63) * 4;
      const int m = half*16 + lrow;
      if (p0 + m < cnt){
        floatx4 v = *(const floatx4*)(epi + lrow*260 + c4);
        *(floatx4*)(out + (size_t)nrow[m]*DM + tile*TD + c4) = v;
      }
    }
    __syncthreads();
  }
}

extern "C" void kernel_launch(void* const* d_in, const int* in_sizes, int n_in,
                              void* d_out, int out_size, void* d_ws, size_t ws_size,
                              hipStream_t stream){
  const float* x      = (const float*)d_in[0];
  const float* w_up   = (const float*)d_in[1];
  const float* b_up   = (const float*)d_in[2];
  const float* w_down = (const float*)d_in[3];
  const float* b_down = (const float*)d_in[4];

  // ws layout (~17.3 MB)
  unsigned short* wupb   = (unsigned short*)d_ws;            // 4096*1024 bf16 = 8 MB
  unsigned short* wdownb = wupb + (size_t)DFF * DM;          // 1024*4096 bf16 = 8 MB
  float* partial = (float*)(wdownb + (size_t)DM * DFF);      // 262144 floats = 1 MB
  float* sig     = partial + 262144;                         // 4096 floats
  int*   ints    = (int*)(sig + 4096);
  int*   winner   = ints;                                    // 16384
  int*   idx      = ints + 16384;                            // 16384
  int*   meta     = ints + 32768;                            // [0..3]=counts [4..7]=offsets
  int*   blk_cnt  = ints + 32776;                            // [64][4]
  int*   blk_base = ints + 33032;                            // [64][4]

  float*          out  = (float*)d_out;
  float*          gate = out + (size_t)N_TOK * DM;
  unsigned short* ob16 = (unsigned short*)d_out;  // row n: hid at n*2048, xbf at n*2048+1024

  k_sig_partial<<<dim3(NT*64), 256, 0, stream>>>(w_up, partial, wupb);
  k_sig_final  <<<dim3(16),    256, 0, stream>>>(partial, sig);
  k_wdown_conv <<<dim3(2048),  256, 0, stream>>>(w_down, wdownb);
  k_route      <<<dim3(N_TOK/4), 256, 0, stream>>>(x, sig, gate, winner, ob16);
  k_hist       <<<dim3(64),    256, 0, stream>>>(winner, blk_cnt);
  k_scan       <<<dim3(1),      64, 0, stream>>>(blk_cnt, meta, blk_base);
  k_scatter    <<<dim3(64),    256, 0, stream>>>(winner, blk_base, idx);
  k_gemm1      <<<dim3(128, 8, NT), 256, 0, stream>>>(ob16, wupb, b_up, meta, idx, ob16);
  k_gemm2      <<<dim3(512, 1, NT), 256, 0, stream>>>(ob16, wdownb, b_down, meta, idx, out);
}

// Round 10
// 273.498 us; speedup vs baseline: 1.1357x; 1.1357x over previous
//
#include <hip/hip_runtime.h>
#include <stdint.h>
#include <stddef.h>

#define N_TOK 16384
#define DM    1024
#define DFF   4096
#define NT    4
#define TU    1024   // d_ff tile
#define TD    256    // d_model tile

typedef __attribute__((ext_vector_type(8))) short  short8;
typedef __attribute__((ext_vector_type(4))) short  short4v;
typedef __attribute__((ext_vector_type(4))) float  floatx4;

__device__ inline unsigned short f2bf(float f){
  union { float f; uint32_t u; } v; v.f = f;
  uint32_t u = v.u + 0x7FFFu + ((v.u >> 16) & 1u);   // RNE
  return (unsigned short)(u >> 16);
}

// async global->LDS, 16B per lane; lds dest is wave-uniform, lane i lands at +16*i
__device__ __forceinline__ void gll16(const void* g, void* l){
  __builtin_amdgcn_global_load_lds(
      (const __attribute__((address_space(1))) unsigned int*)g,
      (__attribute__((address_space(3))) unsigned int*)l,
      16, 0, 0);
}

// ---------------- signatures: partial column sums of w_up + bf16 convert ----
__global__ void k_sig_partial(const float* __restrict__ w_up,
                              float* __restrict__ partial,
                              unsigned short* __restrict__ wupb){
  const int b = blockIdx.x, tid = threadIdx.x;
  const int tile = b >> 6, chunk = b & 63;
  const int c0 = tid * 4;
  const int row0 = tile*TU + chunk*16;
  float s0=0.f, s1=0.f, s2=0.f, s3=0.f;
  const float* base = w_up + (size_t)row0 * DM + c0;
  #pragma unroll
  for (int r = 0; r < 16; ++r){
    floatx4 v = *(const floatx4*)(base + (size_t)r * DM);
    s0 += v[0]; s1 += v[1]; s2 += v[2]; s3 += v[3];
    short4v p;
    p[0]=(short)f2bf(v[0]); p[1]=(short)f2bf(v[1]);
    p[2]=(short)f2bf(v[2]); p[3]=(short)f2bf(v[3]);
    *(short4v*)(wupb + (size_t)(row0 + r) * DM + c0) = p;
  }
  float* p = partial + ((size_t)tile*DM + c0) * 64 + chunk;
  p[0] = s0; p[64] = s1; p[128] = s2; p[192] = s3;
}

__global__ void k_sig_final(const float* __restrict__ partial,
                            float* __restrict__ sig){
  const int g = blockIdx.x * 256 + threadIdx.x;   // 0..4095 = tile*1024+col
  const float* p = partial + (size_t)g * 64;
  float s = 0.f;
  #pragma unroll
  for (int i = 0; i < 64; ++i) s += p[i];
  sig[g] = (s > 0.f) ? 1.f : ((s < 0.f) ? -1.f : 0.f);
}

// ---------------- w_down -> bf16 ------------------------------------------
__global__ void k_wdown_conv(const float* __restrict__ w,
                             unsigned short* __restrict__ wb){
  const size_t i = ((size_t)blockIdx.x * 256 + threadIdx.x) * 8;
  floatx4 v0 = *(const floatx4*)(w + i);
  floatx4 v1 = *(const floatx4*)(w + i + 4);
  short8 p;
  p[0]=(short)f2bf(v0[0]); p[1]=(short)f2bf(v0[1]); p[2]=(short)f2bf(v0[2]); p[3]=(short)f2bf(v0[3]);
  p[4]=(short)f2bf(v1[0]); p[5]=(short)f2bf(v1[1]); p[6]=(short)f2bf(v1[2]); p[7]=(short)f2bf(v1[3]);
  *(short8*)(wb + i) = p;
}

// ---------------- routing: fp64 scores + x->bf16 emit -----------------------
// xbf row n lives in SECOND 2048B of out row n (ushort offset n*2048 + 1024).
__global__ __launch_bounds__(256) void k_route(
    const float* __restrict__ x, const float* __restrict__ sig,
    float* __restrict__ gate_out, int* __restrict__ winner,
    unsigned short* __restrict__ xbf){
  __shared__ float ssig[NT * DM];
  const int tid = threadIdx.x;
  for (int i = tid; i < NT*DM; i += 256) ssig[i] = sig[i];
  __syncthreads();
  const int wv = tid >> 6, lane = tid & 63;
  const int n = blockIdx.x * 4 + wv;
  const float* xr = x + (size_t)n * DM;
  unsigned short* xb = xbf + (size_t)n * 2048 + 1024;
  double a0=0.0, a1=0.0, a2=0.0, a3=0.0;
  #pragma unroll
  for (int j = 0; j < 4; ++j){
    const int c = j*256 + lane*4;
    floatx4 v = *(const floatx4*)(xr + c);
    short4v p;
    p[0]=(short)f2bf(v[0]); p[1]=(short)f2bf(v[1]);
    p[2]=(short)f2bf(v[2]); p[3]=(short)f2bf(v[3]);
    *(short4v*)(xb + c) = p;
    #pragma unroll
    for (int u = 0; u < 4; ++u){
      double xv = (double)v[u];
      a0 += xv * (double)ssig[c+u];
      a1 += xv * (double)ssig[DM   + c+u];
      a2 += xv * (double)ssig[2*DM + c+u];
      a3 += xv * (double)ssig[3*DM + c+u];
    }
  }
  #pragma unroll
  for (int off = 32; off > 0; off >>= 1){
    a0 += __shfl_down(a0, off, 64);
    a1 += __shfl_down(a1, off, 64);
    a2 += __shfl_down(a2, off, 64);
    a3 += __shfl_down(a3, off, 64);
  }
  if (lane == 0){
    double s[4] = {a0, a1, a2, a3};
    int w = 0;
    #pragma unroll
    for (int t = 1; t < 4; ++t) if (s[t] > s[w]) w = t;   // first-max tiebreak
    floatx4 g = { w==0 ? 1.f:0.f, w==1 ? 1.f:0.f, w==2 ? 1.f:0.f, w==3 ? 1.f:0.f };
    *(floatx4*)(gate_out + (size_t)n * 4) = g;
    winner[n] = w;
  }
}

// ---------------- histogram / scan / scatter (atomic-free) ------------------
__global__ void k_hist(const int* __restrict__ winner,
                       int* __restrict__ blk_cnt){   // [64][4]
  __shared__ int wcnt[4][NT];
  const int tid = threadIdx.x, wv = tid >> 6, lane = tid & 63;
  const int w = winner[blockIdx.x * 256 + tid];
  #pragma unroll
  for (int t = 0; t < NT; ++t){
    unsigned long long m = __ballot(w == t);
    if (lane == 0) wcnt[wv][t] = __popcll(m);
  }
  __syncthreads();
  if (tid < NT){
    int s = wcnt[0][tid] + wcnt[1][tid] + wcnt[2][tid] + wcnt[3][tid];
    blk_cnt[blockIdx.x * NT + tid] = s;
  }
}

// scan: parallel coalesced load -> LDS serial scan (fast) -> parallel store.
// (old version did 256 dependent GLOBAL loads on one thread: serial latency)
__global__ void k_scan(const int* __restrict__ blk_cnt,
                       int* __restrict__ meta, int* __restrict__ blk_base){
  __shared__ int s[256];
  const int tid = threadIdx.x;
  s[tid] = blk_cnt[tid];                    // one coalesced load
  __syncthreads();
  if (tid == 0){
    int tot[NT] = {0,0,0,0};
    for (int b = 0; b < 64; ++b)
      for (int t = 0; t < NT; ++t) tot[t] += s[b*NT + t];
    int off = 0, base[NT];
    for (int t = 0; t < NT; ++t){ meta[t] = tot[t]; meta[4+t] = off; base[t] = off; off += tot[t]; }
    for (int b = 0; b < 64; ++b)
      for (int t = 0; t < NT; ++t){ int c = s[b*NT + t]; s[b*NT + t] = base[t]; base[t] += c; }
  }
  __syncthreads();
  blk_base[tid] = s[tid];                   // parallel store
}

__global__ void k_scatter(const int* __restrict__ winner,
                          const int* __restrict__ blk_base,
                          int* __restrict__ idx){
  __shared__ int wcnt[4][NT];
  const int tid = threadIdx.x, wv = tid >> 6, lane = tid & 63;
  const int n = blockIdx.x * 256 + tid;
  const int w = winner[n];
  unsigned long long mymask = 0;
  #pragma unroll
  for (int t = 0; t < NT; ++t){
    unsigned long long m = __ballot(w == t);
    if (lane == 0) wcnt[wv][t] = __popcll(m);
    if (t == w) mymask = m;
  }
  __syncthreads();
  const unsigned long long below = (lane == 0) ? 0ull : (~0ull >> (64 - lane));
  int pos = blk_base[blockIdx.x * NT + w] + __popcll(mymask & below);
  for (int v = 0; v < wv; ++v) pos += wcnt[v][w];
  idx[pos] = n;
}

// ---------------- GEMM1: hid = relu(xbf[rows] @ wupb[tile]^T + b_up) --------
// BM=128 BN=128; gll16 staging, BK=64 paired buffers. launch_bounds(256,2):
// (256,4) measured WORSE (R9: 106us, WRITE_SIZE 2x from L2 thrash) — keep 2.
__global__ __launch_bounds__(256, 2) void k_gemm1(
    const unsigned short* __restrict__ xbf,   // (ushort*)d_out; row n at n*2048+1024
    const unsigned short* __restrict__ wupb,  // [4096][1024] bf16
    const float* __restrict__ b_up, const int* __restrict__ meta,
    const int* __restrict__ idx, unsigned short* __restrict__ hid){
  const int tile = blockIdx.z;
  const int cnt  = meta[tile];
  const int p0   = blockIdx.x * 128;
  if (p0 >= cnt) return;
  const int off  = meta[4 + tile];
  const int nb   = blockIdx.y;

  __shared__ unsigned short smem[16384];  // As0|As1|Bs0|Bs1 (4096 ushorts each); epi overlays
  unsigned short* As0 = smem;
  unsigned short* As1 = smem + 4096;
  unsigned short* Bs0 = smem + 8192;
  unsigned short* Bs1 = smem + 12288;
  __shared__ int nrow[128];

  const int tid = threadIdx.x;
  if (tid < 128){
    int p = p0 + tid;
    nrow[tid] = idx[off + (p < cnt ? p : cnt - 1)];
  }
  __syncthreads();

  const int wv = tid >> 6, lane = tid & 63;
  const int wm = (wv >> 1) * 64, wn = (wv & 1) * 64;
  const int l16 = lane & 15, quad = lane >> 4;

  const int rsub = lane >> 2;          // 0..15
  const int kus  = (lane & 3) * 8;     // ushort offset within 32-elem row

  const int ra = wv*32 + rsub;
  const unsigned short* aptr0 = xbf + (size_t)nrow[ra]      * 2048 + 1024 + kus;
  const unsigned short* aptr1 = xbf + (size_t)nrow[ra + 16] * 2048 + 1024 + kus;
  const unsigned short* bptr0 = wupb + (size_t)(tile*TU + nb*128 + wv*32 + rsub) * DM + kus;
  const unsigned short* bptr1 = bptr0 + 16 * DM;

  // wave-uniform LDS dests ([row][32] layout, 64B row stride)
  unsigned short* a0d0 = As0 + (wv*32) * 32;  unsigned short* a0d1 = a0d0 + 16*32;
  unsigned short* a1d0 = As1 + (wv*32) * 32;  unsigned short* a1d1 = a1d0 + 16*32;
  unsigned short* b0d0 = Bs0 + (wv*32) * 32;  unsigned short* b0d1 = b0d0 + 16*32;
  unsigned short* b1d0 = Bs1 + (wv*32) * 32;  unsigned short* b1d1 = b1d0 + 16*32;

  floatx4 acc[4][4];
  #pragma unroll
  for (int i = 0; i < 4; ++i)
    #pragma unroll
    for (int j = 0; j < 4; ++j) acc[i][j] = (floatx4){0.f,0.f,0.f,0.f};

  for (int k0 = 0; k0 < DM; k0 += 64){
    gll16(aptr0 + k0,      a0d0);
    gll16(aptr1 + k0,      a0d1);
    gll16(aptr0 + k0 + 32, a1d0);
    gll16(aptr1 + k0 + 32, a1d1);
    gll16(bptr0 + k0,      b0d0);
    gll16(bptr1 + k0,      b0d1);
    gll16(bptr0 + k0 + 32, b1d0);
    gll16(bptr1 + k0 + 32, b1d1);
    __syncthreads();
    {
      short8 af[4], bfr[4];
      #pragma unroll
      for (int i = 0; i < 4; ++i) af[i]  = *(const short8*)(As0 + (wm + i*16 + l16)*32 + quad*8);
      #pragma unroll
      for (int j = 0; j < 4; ++j) bfr[j] = *(const short8*)(Bs0 + (wn + j*16 + l16)*32 + quad*8);
      #pragma unroll
      for (int i = 0; i < 4; ++i)
        #pragma unroll
        for (int j = 0; j < 4; ++j)
          acc[i][j] = __builtin_amdgcn_mfma_f32_16x16x32_bf16(af[i], bfr[j], acc[i][j], 0, 0, 0);
    }
    {
      short8 af[4], bfr[4];
      #pragma unroll
      for (int i = 0; i < 4; ++i) af[i]  = *(const short8*)(As1 + (wm + i*16 + l16)*32 + quad*8);
      #pragma unroll
      for (int j = 0; j < 4; ++j) bfr[j] = *(const short8*)(Bs1 + (wn + j*16 + l16)*32 + quad*8);
      #pragma unroll
      for (int i = 0; i < 4; ++i)
        #pragma unroll
        for (int j = 0; j < 4; ++j)
          acc[i][j] = __builtin_amdgcn_mfma_f32_16x16x32_bf16(af[i], bfr[j], acc[i][j], 0, 0, 0);
    }
    __syncthreads();
  }

  // epilogue: two half-passes of 64 rows through LDS (pad stride 136), wide stores
  const int gcol0 = nb*128;
  #pragma unroll
  for (int half = 0; half < 2; ++half){
    if ((wv >> 1) == half){
      #pragma unroll
      for (int i = 0; i < 4; ++i){
        #pragma unroll
        for (int j = 0; j < 4; ++j){
          const int col = wn + j*16 + l16;          // 0..127
          const float bias = b_up[tile*TU + gcol0 + col];
          #pragma unroll
          for (int r = 0; r < 4; ++r){
            const int lrow = i*16 + quad*4 + r;     // 0..63
            float v = acc[i][j][r] + bias;
            smem[lrow*136 + col] = f2bf(v > 0.f ? v : 0.f);
          }
        }
      }
    }
    __syncthreads();
    // 64 rows x 16 chunks of 8 ushorts (128 cols)
    #pragma unroll
    for (int c = tid; c < 1024; c += 256){
      const int lrow = c >> 4, k8 = (c & 15) * 8;
      const int m = half*64 + lrow;
      if (p0 + m < cnt){
        short8 vv = *(const short8*)(smem + lrow*136 + k8);
        *(short8*)(hid + (size_t)nrow[m]*2048 + gcol0 + k8) = vv;
      }
    }
    __syncthreads();
  }
}

// ---------------- GEMM2: out = hid @ wdownb[tile]^T + b_down + zero-fill ----
// BM=32 BN=256, BK=64 paired buffers (16 iters x 16 MFMA). Zero-fill fused
// after the K-loop's final barrier (all hid global reads drained; each
// token's hid is read by exactly this one block).
__global__ __launch_bounds__(256, 2) void k_gemm2(
    const unsigned short* __restrict__ hid,    // (ushort*)d_out; row n at n*2048
    const unsigned short* __restrict__ wdownb, // [1024][4096] bf16
    const float* __restrict__ b_down, const int* __restrict__ meta,
    const int* __restrict__ idx, float* __restrict__ out){
  const int tile = blockIdx.z;
  const int cnt  = meta[tile];
  const int p0   = blockIdx.x * 32;
  if (p0 >= cnt) return;
  const int off  = meta[4 + tile];

  __shared__ unsigned short smem[18432];  // As0|As1 (1024 each) | Bs0|Bs1 (8192 each)
  unsigned short* As0 = smem;
  unsigned short* As1 = smem + 1024;
  unsigned short* Bs0 = smem + 2048;
  unsigned short* Bs1 = smem + 10240;
  float* epi = (float*)smem;              // overlay: 16 rows x 260 floats = 16640B
  __shared__ int nrow[32];

  const int tid = threadIdx.x;
  if (tid < 32){
    int p = p0 + tid;
    nrow[tid] = idx[off + (p < cnt ? p : cnt - 1)];
  }
  __syncthreads();

  const int wv = tid >> 6, lane = tid & 63;
  const int wn = wv * 64;
  const int l16 = lane & 15, quad = lane >> 4;

  const int rsub = lane >> 2;
  const int kus  = (lane & 3) * 8;

  // A: waves 0,1 stage chunk0 (rows 0-15 / 16-31); waves 2,3 stage chunk1
  const int arow = (wv & 1)*16 + rsub;
  const unsigned short* aptr = hid + (size_t)nrow[arow] * 2048 + kus;
  const int aoff = (wv >> 1) * 32;                     // k-chunk offset
  unsigned short* asd = (wv < 2 ? As0 : As1) + ((wv & 1)*16) * 32;
  // B: 256 rows, 64 per wave per chunk
  const unsigned short* bptr = wdownb + (size_t)(tile*TD + wv*64 + rsub) * DFF + tile*TU + kus;
  unsigned short* bsd0 = Bs0 + (wv*64) * 32;
  unsigned short* bsd1 = Bs1 + (wv*64) * 32;

  floatx4 acc[2][4];
  #pragma unroll
  for (int i = 0; i < 2; ++i)
    #pragma unroll
    for (int j = 0; j < 4; ++j) acc[i][j] = (floatx4){0.f,0.f,0.f,0.f};

  for (int k0 = 0; k0 < TU; k0 += 64){
    gll16(aptr + k0 + aoff, asd);
    gll16(bptr + k0,               bsd0);
    gll16(bptr + k0 + 16*DFF,      bsd0 + 16*32);
    gll16(bptr + k0 + 32*DFF,      bsd0 + 32*32);
    gll16(bptr + k0 + 48*DFF,      bsd0 + 48*32);
    gll16(bptr + k0 + 32,          bsd1);
    gll16(bptr + k0 + 32 + 16*DFF, bsd1 + 16*32);
    gll16(bptr + k0 + 32 + 32*DFF, bsd1 + 32*32);
    gll16(bptr + k0 + 32 + 48*DFF, bsd1 + 48*32);
    __syncthreads();
    {
      short8 af[2], bfr[4];
      #pragma unroll
      for (int i = 0; i < 2; ++i) af[i]  = *(const short8*)(As0 + (i*16 + l16)*32 + quad*8);
      #pragma unroll
      for (int j = 0; j < 4; ++j) bfr[j] = *(const short8*)(Bs0 + (wn + j*16 + l16)*32 + quad*8);
      #pragma unroll
      for (int i = 0; i < 2; ++i)
        #pragma unroll
        for (int j = 0; j < 4; ++j)
          acc[i][j] = __builtin_amdgcn_mfma_f32_16x16x32_bf16(af[i], bfr[j], acc[i][j], 0, 0, 0);
    }
    {
      short8 af[2], bfr[4];
      #pragma unroll
      for (int i = 0; i < 2; ++i) af[i]  = *(const short8*)(As1 + (i*16 + l16)*32 + quad*8);
      #pragma unroll
      for (int j = 0; j < 4; ++j) bfr[j] = *(const short8*)(Bs1 + (wn + j*16 + l16)*32 + quad*8);
      #pragma unroll
      for (int i = 0; i < 2; ++i)
        #pragma unroll
        for (int j = 0; j < 4; ++j)
          acc[i][j] = __builtin_amdgcn_mfma_f32_16x16x32_bf16(af[i], bfr[j], acc[i][j], 0, 0, 0);
    }
    __syncthreads();
  }

  // zero-fill non-winner 256-col blocks of OWN tokens (hid reads all drained)
  const floatx4 z4 = {0.f, 0.f, 0.f, 0.f};
  #pragma unroll
  for (int cb = 0; cb < 4; ++cb){
    if (cb == tile) continue;
    for (int c = tid; c < 32*64; c += 256){
      const int rowl = c >> 6, c4 = (c & 63) * 4;
      if (p0 + rowl < cnt)
        *(floatx4*)(out + (size_t)nrow[rowl]*DM + cb*256 + c4) = z4;
    }
  }

  // epilogue: two half-passes of 16 rows via LDS fp32 (pad stride 260), float4 stores
  #pragma unroll
  for (int half = 0; half < 2; ++half){
    #pragma unroll
    for (int j = 0; j < 4; ++j){
      const int col = wn + j*16 + l16;              // 0..255
      const float bias = b_down[tile*TD + col];
      #pragma unroll
      for (int r = 0; r < 4; ++r){
        const int lrow = quad*4 + r;                // 0..15
        epi[lrow*260 + col] = acc[half][j][r] + bias;
      }
    }
    __syncthreads();
    #pragma unroll
    for (int c = tid; c < 1024; c += 256){          // 16 rows x 64 float4 chunks
      const int lrow = c >> 6, c4 = (c & 63) * 4;
      const int m = half*16 + lrow;
      if (p0 + m < cnt){
        floatx4 v = *(const floatx4*)(epi + lrow*260 + c4);
        *(floatx4*)(out + (size_t)nrow[m]*DM + tile*TD + c4) = v;
      }
    }
    __syncthreads();
  }
}

extern "C" void kernel_launch(void* const* d_in, const int* in_sizes, int n_in,
                              void* d_out, int out_size, void* d_ws, size_t ws_size,
                              hipStream_t stream){
  const float* x      = (const float*)d_in[0];
  const float* w_up   = (const float*)d_in[1];
  const float* b_up   = (const float*)d_in[2];
  const float* w_down = (const float*)d_in[3];
  const float* b_down = (const float*)d_in[4];

  // ws layout (~17.3 MB)
  unsigned short* wupb   = (unsigned short*)d_ws;            // 4096*1024 bf16 = 8 MB
  unsigned short* wdownb = wupb + (size_t)DFF * DM;          // 1024*4096 bf16 = 8 MB
  float* partial = (float*)(wdownb + (size_t)DM * DFF);      // 262144 floats = 1 MB
  float* sig     = partial + 262144;                         // 4096 floats
  int*   ints    = (int*)(sig + 4096);
  int*   winner   = ints;                                    // 16384
  int*   idx      = ints + 16384;                            // 16384
  int*   meta     = ints + 32768;                            // [0..3]=counts [4..7]=offsets
  int*   blk_cnt  = ints + 32776;                            // [64][4]
  int*   blk_base = ints + 33032;                            // [64][4]

  float*          out  = (float*)d_out;
  float*          gate = out + (size_t)N_TOK * DM;
  unsigned short* ob16 = (unsigned short*)d_out;  // row n: hid at n*2048, xbf at n*2048+1024

  k_sig_partial<<<dim3(NT*64), 256, 0, stream>>>(w_up, partial, wupb);
  k_sig_final  <<<dim3(16),    256, 0, stream>>>(partial, sig);
  k_wdown_conv <<<dim3(2048),  256, 0, stream>>>(w_down, wdownb);
  k_route      <<<dim3(N_TOK/4), 256, 0, stream>>>(x, sig, gate, winner, ob16);
  k_hist       <<<dim3(64),    256, 0, stream>>>(winner, blk_cnt);
  k_scan       <<<dim3(1),     256, 0, stream>>>(blk_cnt, meta, blk_base);
  k_scatter    <<<dim3(64),    256, 0, stream>>>(winner, blk_base, idx);
  k_gemm1      <<<dim3(128, 8, NT), 256, 0, stream>>>(ob16, wupb, b_up, meta, idx, ob16);
  k_gemm2      <<<dim3(512, 1, NT), 256, 0, stream>>>(ob16, wdownb, b_down, meta, idx, out);
}